// Round 7
// baseline (502.149 us; speedup 1.0000x reference)
//
#include <hip/hip_runtime.h>

// DynamicRouting: grouped 1x1 conv (G=8, FI=FO=64) + 3-iter sigmoid routing.
// v7: conv de-stalled. v6 post-mortem: split worked (conv 164us @72% occ,
// route ~77us); conv gated by mixed lgkmcnt waits -- ds_read (x in LDS) and
// s_load (weights) share lgkmcnt, SMEM is out-of-order => conservative
// lgkmcnt(0) drains serialize the inner loop (VALUBusy 38%).
// Fix: x column loaded DIRECTLY into VGPRs (64 coalesced global_load_dword,
// vmcnt-counted, 64-deep ILP, no LDS, no barrier); inner loop is pure
// s_load+FMA. 4 waves/WG re-load the same 16KB tile -> L1/L2 dedup
// (falsifier: FETCH >> 134MB). Route kernel unchanged from v6 (~77us,
// near BW floor). Fallback fused kernel (v5) kept for small ws.

#define NG 8
#define NFO 64
#define NFI 64
#define NB 32
#define NH 64
#define NW 64
#define HW (NH * NW)   // 4096 pixels per (b, channel) plane

typedef float v2f __attribute__((ext_vector_type(2)));

__device__ __forceinline__ void stage_piece(const float* gsrc, float* ldst) {
    // per-lane global src; wave-uniform LDS dst: lane L writes 16B at ldst+L*16
    __builtin_amdgcn_global_load_lds(
        (const __attribute__((address_space(1))) void*)gsrc,
        (__attribute__((address_space(3))) void*)ldst, 16, 0, 0);
}

// ---------------------------------------------------------------------------
// K1: grouped 1x1 conv.  con[b][g][fo][px] = sum_i w[g][fo][i] * x[b][g*64+i][px]
// Grid = 32 b x 8 g x 64 px-tiles = 16384 WGs, 256 threads.
// Thread = (px p in tile, fo-quarter q). x column in xr[32] v2f (64 VGPRs),
// loaded via 64 coalesced global_load_dword (256B/wave-inst). Weights are
// wave-uniform -> s_load; no ds ops anywhere => no lgkmcnt cross-serialization.
// ---------------------------------------------------------------------------
__global__ __launch_bounds__(256) void conv_kernel(
    const float* __restrict__ x, const float* __restrict__ weight,
    float* __restrict__ con)
{
    const int tid = threadIdx.x;
    const int p = tid & 63;
    const int q = __builtin_amdgcn_readfirstlane(tid >> 6);  // fo-quarter

    const int id = blockIdx.x;
    const int t = id & 63;          // px tile (64 px)
    const int g = (id >> 6) & 7;    // group
    const int b = id >> 9;          // batch

    // this thread's pixel column: x[b][g*64 + ch][t*64 + p], ch = 0..63
    const float* xcol = x + ((size_t)b * (NG * NFI) + (size_t)g * NFI) * HW
                          + t * 64 + p;

    v2f xr[32];
#pragma unroll
    for (int c2 = 0; c2 < 32; ++c2) {
        xr[c2].x = xcol[(size_t)(2 * c2) * HW];
        xr[c2].y = xcol[(size_t)(2 * c2 + 1) * HW];
    }

    const float* wq = weight + ((size_t)g * NFO + (size_t)q * 16) * NFI;
    float* crow = con + (((size_t)(b * NG + g) * NFO + (size_t)q * 16)) * HW
                      + t * 64 + p;

#pragma unroll
    for (int f = 0; f < 16; ++f) {
        const float* wr = wq + (size_t)f * NFI;   // wave-uniform -> s_load
        v2f a0 = {0.f, 0.f}, a1 = {0.f, 0.f};
#pragma unroll
        for (int c2 = 0; c2 < 32; c2 += 2) {
            const v2f w0 = *(const v2f*)(wr + 2 * c2);
            const v2f w1 = *(const v2f*)(wr + 2 * c2 + 2);
            a0 = __builtin_elementwise_fma(w0, xr[c2], a0);
            a1 = __builtin_elementwise_fma(w1, xr[c2 + 1], a1);
        }
        crow[(size_t)f * HW] = (a0.x + a1.x) + (a0.y + a1.y);  // coalesced dword
    }
}

// ---------------------------------------------------------------------------
// K2: routing. Grid = 32 b x 64 px-tiles = 2048 WGs, 256 threads.
// Thread = (px p, fo-quarter q): streams con[8][16] (coalesced, stride HW),
// then the v5 routing block verbatim. BW-bound (~300MB); ~77us measured.
// ---------------------------------------------------------------------------
__global__ __launch_bounds__(256) void route_kernel(
    const float* __restrict__ con, const float* __restrict__ bias,
    float* __restrict__ out)
{
    const int tid = threadIdx.x;
    const int p = tid & 63;
    const int q = __builtin_amdgcn_readfirstlane(tid >> 6);

    const int id = blockIdx.x;
    const int t = id & 63;          // px tile = h
    const int b = id >> 6;

    __shared__ float pbuf[4][8][64];
    __shared__ float alphaS[8][64];
    __shared__ float betaS[8][64];

    float c[8][16];
#pragma unroll
    for (int g = 0; g < 8; ++g) {
        const float* cr = con + (((size_t)(b * NG + g) * NFO + (size_t)q * 16)) * HW
                              + t * 64 + p;
#pragma unroll
        for (int f = 0; f < 16; ++f) c[g][f] = cr[(size_t)f * HW];
    }

    float v[16];

    // iter 0: alpha = sigmoid(0) = 0.5; v0 = 0.5 * sum_g con
#pragma unroll
    for (int f = 0; f < 16; ++f) {
        float s = c[0][f];
#pragma unroll
        for (int g = 1; g < 8; ++g) s += c[g][f];
        v[f] = 0.5f * s;
    }
#pragma unroll
    for (int g = 0; g < 8; ++g) {
        float s = 0.f;
#pragma unroll
        for (int f = 0; f < 16; ++f) s = fmaf(v[f], c[g][f], s);
        pbuf[q][g][p] = s;
    }
    __syncthreads();
    for (int k = tid; k < 512; k += 256) {
        const int gg = k >> 6, pp = k & 63;
        const float bs = pbuf[0][gg][pp] + pbuf[1][gg][pp] +
                         pbuf[2][gg][pp] + pbuf[3][gg][pp];
        betaS[gg][pp] = bs;
        alphaS[gg][pp] = 1.f / (1.f + __expf(-bs));
    }
    __syncthreads();

    // iter 1
    float a[8];
#pragma unroll
    for (int g = 0; g < 8; ++g) a[g] = alphaS[g][p];
#pragma unroll
    for (int f = 0; f < 16; ++f) {
        float s = 0.f;
#pragma unroll
        for (int g = 0; g < 8; ++g) s = fmaf(a[g], c[g][f], s);
        v[f] = s;
    }
#pragma unroll
    for (int g = 0; g < 8; ++g) {
        float s = 0.f;
#pragma unroll
        for (int f = 0; f < 16; ++f) s = fmaf(v[f], c[g][f], s);
        pbuf[q][g][p] = s;
    }
    __syncthreads();
    for (int k = tid; k < 512; k += 256) {
        const int gg = k >> 6, pp = k & 63;
        const float bs = betaS[gg][pp] +
                         pbuf[0][gg][pp] + pbuf[1][gg][pp] +
                         pbuf[2][gg][pp] + pbuf[3][gg][pp];
        alphaS[gg][pp] = 1.f / (1.f + __expf(-bs));
    }
    __syncthreads();

    // iter 2: out = sum_g alpha2*con + bias
#pragma unroll
    for (int g = 0; g < 8; ++g) a[g] = alphaS[g][p];

    const float* bq = bias + q * 16;
    float* orow = out + (((size_t)b * NFO + (size_t)q * 16) * NH + t) * NW + p;
#pragma unroll
    for (int f = 0; f < 16; ++f) {
        float s = bq[f];
#pragma unroll
        for (int g = 0; g < 8; ++g) s = fmaf(a[g], c[g][f], s);
        orow[(size_t)f * HW] = s;
    }
}

// ---------------------------------------------------------------------------
// Fallback: v5 fused kernel verbatim (known-good 305 us) for small ws.
// ---------------------------------------------------------------------------
__global__ __launch_bounds__(256) void dynrout_kernel(
    const float* __restrict__ x, const float* __restrict__ weight,
    const float* __restrict__ bias, float* __restrict__ out)
{
    const int tid = threadIdx.x;
    const int p = tid & 63;
    const int q = __builtin_amdgcn_readfirstlane(tid >> 6);

    const int wg = blockIdx.x;
    const int b = wg >> 6;
    const int h = wg & 63;

    __shared__ __align__(16) float smem[6144];  // 24 KiB: 3 x 8KB chunk ring

    const float* xrow = x + (size_t)b * (NG * NFI) * HW + (size_t)h * NW;
    const float* gpiece = xrow + (size_t)(p >> 4) * HW + (size_t)(p & 15) * 4;

    float con[8][16];
#pragma unroll
    for (int g = 0; g < 8; ++g)
#pragma unroll
        for (int f = 0; f < 16; ++f) con[g][f] = 0.f;

#pragma unroll
    for (int cc = 0; cc < 2; ++cc) {
        float* dst = smem + cc * 2048;
        const float* g0 = gpiece + (size_t)(cc * 32) * HW;
        stage_piece(g0 + (size_t)(q * 8) * HW,     dst + (q * 2) * 256);
        stage_piece(g0 + (size_t)(q * 8 + 4) * HW, dst + (q * 2 + 1) * 256);
    }

#pragma unroll
    for (int c = 0; c < 16; ++c) {
        if (c < 15) asm volatile("s_waitcnt vmcnt(2)" ::: "memory");
        else        asm volatile("s_waitcnt vmcnt(0)" ::: "memory");
        __builtin_amdgcn_s_barrier();

        if (c < 14) {
            float* dst = smem + ((c + 2) % 3) * 2048;
            const float* g0 = gpiece + (size_t)((c + 2) * 32) * HW;
            stage_piece(g0 + (size_t)(q * 8) * HW,     dst + (q * 2) * 256);
            stage_piece(g0 + (size_t)(q * 8 + 4) * HW, dst + (q * 2 + 1) * 256);
        }

        const int g = c >> 1;
        const float* bufp = smem + (c % 3) * 2048;

        v2f xp[16];
#pragma unroll
        for (int jp = 0; jp < 16; ++jp) {
            xp[jp].x = bufp[(2 * jp) * 64 + p];
            xp[jp].y = bufp[(2 * jp + 1) * 64 + p];
        }

        const float* wq = weight + ((size_t)g * NFO + (size_t)q * 16) * NFI + (c & 1) * 32;
#pragma unroll
        for (int f = 0; f < 16; ++f) {
            const float* wr = wq + (size_t)f * NFI;
            v2f a0 = {0.f, 0.f}, a1 = {0.f, 0.f};
#pragma unroll
            for (int jp = 0; jp < 16; jp += 2) {
                const v2f w0 = *(const v2f*)(wr + 2 * jp);
                const v2f w1 = *(const v2f*)(wr + 2 * jp + 2);
                a0 = __builtin_elementwise_fma(w0, xp[jp], a0);
                a1 = __builtin_elementwise_fma(w1, xp[jp + 1], a1);
            }
            con[g][f] += (a0.x + a1.x) + (a0.y + a1.y);
        }
    }
    __syncthreads();

    float* pbuf   = smem;
    float* alphaS = smem + 2048;
    float* betaS  = smem + 2560;

    float v[16];
#pragma unroll
    for (int f = 0; f < 16; ++f) {
        float s = con[0][f];
#pragma unroll
        for (int g = 1; g < 8; ++g) s += con[g][f];
        v[f] = 0.5f * s;
    }
#pragma unroll
    for (int g = 0; g < 8; ++g) {
        float s = 0.f;
#pragma unroll
        for (int f = 0; f < 16; ++f) s = fmaf(v[f], con[g][f], s);
        pbuf[(q * 8 + g) * 64 + p] = s;
    }
    __syncthreads();
    for (int k = tid; k < 512; k += 256) {
        const int gg = k >> 6, pp = k & 63;
        const float bs = pbuf[gg * 64 + pp] + pbuf[512 + gg * 64 + pp] +
                         pbuf[1024 + gg * 64 + pp] + pbuf[1536 + gg * 64 + pp];
        betaS[gg * 64 + pp] = bs;
        alphaS[gg * 64 + pp] = 1.f / (1.f + __expf(-bs));
    }
    __syncthreads();

    float a[8];
#pragma unroll
    for (int g = 0; g < 8; ++g) a[g] = alphaS[g * 64 + p];
#pragma unroll
    for (int f = 0; f < 16; ++f) {
        float s = 0.f;
#pragma unroll
        for (int g = 0; g < 8; ++g) s = fmaf(a[g], con[g][f], s);
        v[f] = s;
    }
#pragma unroll
    for (int g = 0; g < 8; ++g) {
        float s = 0.f;
#pragma unroll
        for (int f = 0; f < 16; ++f) s = fmaf(v[f], con[g][f], s);
        pbuf[(q * 8 + g) * 64 + p] = s;
    }
    __syncthreads();
    for (int k = tid; k < 512; k += 256) {
        const int gg = k >> 6, pp = k & 63;
        const float bs = betaS[gg * 64 + pp] +
                         pbuf[gg * 64 + pp] + pbuf[512 + gg * 64 + pp] +
                         pbuf[1024 + gg * 64 + pp] + pbuf[1536 + gg * 64 + pp];
        alphaS[gg * 64 + pp] = 1.f / (1.f + __expf(-bs));
    }
    __syncthreads();

#pragma unroll
    for (int g = 0; g < 8; ++g) a[g] = alphaS[g * 64 + p];

    const float* bq = bias + q * 16;
    float* orow = out + (((size_t)b * NFO + (size_t)q * 16) * NH + h) * NW + p;
#pragma unroll
    for (int f = 0; f < 16; ++f) {
        float s = bq[f];
#pragma unroll
        for (int g = 0; g < 8; ++g) s = fmaf(a[g], con[g][f], s);
        orow[(size_t)f * HW] = s;
    }
}

extern "C" void kernel_launch(void* const* d_in, const int* in_sizes, int n_in,
                              void* d_out, int out_size, void* d_ws, size_t ws_size,
                              hipStream_t stream) {
    const float* x      = (const float*)d_in[0];
    const float* weight = (const float*)d_in[1];
    const float* bias   = (const float*)d_in[2];
    float* out = (float*)d_out;

    const size_t need = (size_t)NB * NG * NFO * HW * sizeof(float);  // 268 MB
    if (d_ws != nullptr && ws_size >= need) {
        float* con = (float*)d_ws;
        conv_kernel<<<dim3(NB * NG * 64), dim3(256), 0, stream>>>(x, weight, con);
        route_kernel<<<dim3(NB * 64), dim3(256), 0, stream>>>(con, bias, out);
    } else {
        dynrout_kernel<<<dim3(NB * NH), dim3(256), 0, stream>>>(x, weight, bias, out);
    }
}